// Round 4
// baseline (655.645 us; speedup 1.0000x reference)
//
#include <hip/hip_runtime.h>
#include <hip/hip_bf16.h>
#include <stdint.h>

#define N_TOK 4096
#define DIM   1024
#define NE    8
#define HID   4096
#define OUTD  1024
#define TOPK  2
#define SLOTS (N_TOK*TOPK)
#define SLOTS_PAD (SLOTS+256)

typedef __bf16 bf16_t;
typedef __attribute__((ext_vector_type(8))) __bf16 bf16x8;
typedef __attribute__((ext_vector_type(4))) __bf16 bf16x4;
typedef __attribute__((ext_vector_type(4))) float  f32x4;

// ---------------- fused gating (fp64 logits, top-2, softmax) + x -> bf16 cast ----------------
__global__ void k_gatecast(const float* __restrict__ x, const float* __restrict__ wg,
                           bf16_t* __restrict__ xb,
                           int* __restrict__ tki, float* __restrict__ tkg,
                           int* __restrict__ counts) {
    int n = blockIdx.x;
    int lane = threadIdx.x;            // 64 threads = 1 wave
    const float* xr = x + (size_t)n * DIM;
    double acc[NE];
#pragma unroll
    for (int e = 0; e < NE; ++e) acc[e] = 0.0;
#pragma unroll
    for (int i = 0; i < 4; ++i) {
        int d0 = i * 256 + lane * 4;
        float4 v = *(const float4*)&xr[d0];
        bf16x4 o;
        o[0] = (__bf16)v.x; o[1] = (__bf16)v.y; o[2] = (__bf16)v.z; o[3] = (__bf16)v.w;
        *(bf16x4*)&xb[(size_t)n * DIM + d0] = o;
        const float* wr = wg + (size_t)d0 * NE;
#pragma unroll
        for (int j = 0; j < 4; ++j) {
            double xv = (double)((&v.x)[j]);
#pragma unroll
            for (int e = 0; e < NE; ++e) acc[e] += xv * (double)wr[j * NE + e];
        }
    }
#pragma unroll
    for (int e = 0; e < NE; ++e)
        for (int off = 32; off > 0; off >>= 1) acc[e] += __shfl_xor(acc[e], off);
    if (lane == 0) {
        int i0 = 0; double v0 = acc[0];
#pragma unroll
        for (int e = 1; e < NE; ++e) if (acc[e] > v0) { v0 = acc[e]; i0 = e; }
        int i1 = -1; double v1 = -1e300;
#pragma unroll
        for (int e = 0; e < NE; ++e) if (e != i0 && acc[e] > v1) { v1 = acc[e]; i1 = e; }
        double e1 = exp(v1 - v0);
        double s = 1.0 + e1;
        tki[n*2]   = i0;  tki[n*2+1] = i1;
        tkg[n*2]   = (float)(1.0 / s);
        tkg[n*2+1] = (float)(e1 / s);
        atomicAdd(&counts[i0], 1);
        atomicAdd(&counts[i1], 1);
    }
}

// ---------------- importance: deterministic per-expert reduction ----------------
__global__ void k_importance(const int* __restrict__ tki, const float* __restrict__ tkg,
                             float* __restrict__ imp) {
    int e = blockIdx.x, t = threadIdx.x;
    __shared__ float red[256];
    float s = 0.f;
    for (int i = t; i < SLOTS; i += 256) s += (tki[i] == e) ? tkg[i] : 0.f;
    red[t] = s; __syncthreads();
    for (int off = 128; off > 0; off >>= 1) {
        if (t < off) red[t] += red[t + off];
        __syncthreads();
    }
    if (t == 0) imp[e] = red[0];
}

// ---------------- aux loss + prefix-sum bases ----------------
__global__ void k_finalize(const float* __restrict__ imp, const int* __restrict__ counts,
                           int* __restrict__ bases, float* __restrict__ aux_out) {
    if (threadIdx.x == 0 && blockIdx.x == 0) {
        float m = 0.f;
        for (int e = 0; e < NE; ++e) m += imp[e];
        m /= (float)NE;
        float var = 0.f;
        for (int e = 0; e < NE; ++e) { float d = imp[e] - m; var += d * d; }
        var /= (float)NE;
        aux_out[0] = 0.01f * var / (m * m + 1e-10f);
        int b = 0;
        for (int e = 0; e < NE; ++e) { bases[e] = b; b += counts[e]; }
    }
}

// ---------------- build per-expert token lists ----------------
__global__ void k_build(const int* __restrict__ tki, const float* __restrict__ tkg,
                        const int* __restrict__ bases, int* __restrict__ cursor,
                        int* __restrict__ tok_ids, float* __restrict__ sgate) {
    int i = blockIdx.x * 256 + threadIdx.x;
    if (i < SLOTS) {
        int e = tki[i];
        int p = atomicAdd(&cursor[e], 1);
        int s = bases[e] + p;
        tok_ids[s] = i >> 1;
        sgate[s]   = tkg[i];
    }
}

// ---------------- W [E][R][C] fp32 -> Wt [E][C][R] bf16, 64x64 tiles ----------------
__global__ void k_transpose(const float* __restrict__ src, bf16_t* __restrict__ dst,
                            int R, int C) {
    __shared__ float tile[64][65];
    const size_t slab = (size_t)R * C;
    const float* s = src + slab * blockIdx.z;
    bf16_t*      d = dst + slab * blockIdx.z;
    int c0 = blockIdx.x * 64, r0 = blockIdx.y * 64;
    int tx = threadIdx.x & 15;
    int ty = threadIdx.x >> 4;
#pragma unroll
    for (int p = 0; p < 4; ++p) {
        int rr = p * 16 + ty;
        float4 v = *(const float4*)&s[(size_t)(r0 + rr) * C + c0 + tx * 4];
        tile[rr][tx*4+0] = v.x; tile[rr][tx*4+1] = v.y;
        tile[rr][tx*4+2] = v.z; tile[rr][tx*4+3] = v.w;
    }
    __syncthreads();
#pragma unroll
    for (int p = 0; p < 4; ++p) {
        int rr = p * 16 + ty;          // dst row (= source column)
        int cc = tx * 4;               // dst col (= source row)
        bf16x4 o;
        o[0] = (__bf16)tile[cc+0][rr]; o[1] = (__bf16)tile[cc+1][rr];
        o[2] = (__bf16)tile[cc+2][rr]; o[3] = (__bf16)tile[cc+3][rr];
        *(bf16x4*)&d[(size_t)(c0 + rr) * R + r0 + cc] = o;
    }
}

// ---------------- grouped GEMM, 256x256 tile, BK=64, 8 waves (2M x 4N) ----------------
// m201-class structure: per K-tile 3 windows, one s_barrier each:
//   W0: stage A'(4 gll) | read fa(mh0)8 + fb(all)8 | 16 MFMA q0
//   W1: stage B'(4 gll) | read fa(mh1)8            | 16 MFMA q1
//   W2:                                              32 MFMA q2+q3 | vmcnt(0) | adv
// vmcnt(0) fires when prefetch is 2-3 windows old (near-free), never in read path.
// LDS swizzle both-sides (rule #21): physcol = col ^ ((row&7)<<3); gll source
// pre-permuted with lcol = ((L&7)^(L>>3))<<3 so linear lane writes land right.
// y-persistent loop kills dead blocks; expert pinned to XCD via bid&7.
template <int MODE>
__global__ __launch_bounds__(512, 2)
void k_gemm(const bf16_t* __restrict__ A,    // MODE0: xb [N][DIM]; MODE1: hbuf [SLOTS_PAD][HID]
            const bf16_t* __restrict__ Bt,   // MODE0: w1t [E][HID][DIM]; MODE1: w2t [E][OUTD][HID]
            const float* __restrict__ bias,  // MODE0: b1 [E][HID]; MODE1: b2 [E][OUTD]
            const int* __restrict__ tok_ids,
            const float* __restrict__ sgate,
            const int* __restrict__ bases,
            const int* __restrict__ counts,
            bf16_t* __restrict__ hbuf,
            float* __restrict__ out) {
    constexpr int KD = (MODE == 0) ? DIM : HID;
    constexpr int ND = (MODE == 0) ? HID : OUTD;
    constexpr int NP = ND / 256;            // panels per expert: 16 / 4
    constexpr int KT = KD / 64;             // K-tiles: 16 / 64
    constexpr int ABUF = 256 * 64;          // elems per buffer (16384)

    const int e    = blockIdx.x & 7;        // expert pinned to XCD
    const int rest = blockIdx.x >> 3;
    const int panel = rest % NP;
    const int z     = rest / NP;            // [0,4)
    const int ne = counts[e];
    if (ne == 0) return;
    const int b0 = bases[e];
    const int n0 = panel * 256;

    extern __shared__ bf16_t lds[];         // 2*ABUF (A) + 2*ABUF (B) = 128 KB
    bf16_t* lA = lds;
    bf16_t* lB = lds + 2 * ABUF;

    const int t = threadIdx.x, w = t >> 6, L = t & 63;
    const int wm = w >> 2, wn = w & 3;      // 2 x 4 wave grid
    const int lr = L & 15, lq = L >> 4;

    // staging geometry: instr (h,q): rows h*128 + (w*2+q)*8 + (L>>3)
    const int artq0 = (w * 2) * 8 + (L >> 3);       // row within half, q=0
    const int lcol  = (((L & 7) ^ (L >> 3)) << 3);  // pre-swizzled source col (elems)

    // B source pointers (rows fixed per block)
    const bf16_t* bsrc[2][2];
#pragma unroll
    for (int h = 0; h < 2; ++h)
#pragma unroll
        for (int q = 0; q < 2; ++q)
            bsrc[h][q] = Bt + ((size_t)e * ND + n0 + h * 128 + artq0 + q * 8) * KD + lcol;

    // fragment-read swizzled column bases (per thread)
    const int sw  = (lr & 7) << 3;
    const int pc0 = (lq * 8) ^ sw;          // kk=0 column; kk=1 adds ^32

    // per-wave LDS stage destinations (wave-uniform)
    const int dstA[2][2] = {{(0 * 128 + (w*2+0)*8) * 64, (0 * 128 + (w*2+1)*8) * 64},
                            {(1 * 128 + (w*2+0)*8) * 64, (1 * 128 + (w*2+1)*8) * 64}};

#define GLL(srcp, dstp) __builtin_amdgcn_global_load_lds( \
        (const __attribute__((address_space(1))) uint32_t*)(srcp), \
        (__attribute__((address_space(3))) uint32_t*)(dstp), 16, 0, 0)

    // ---------------- y-persistent loop ----------------
    for (int y = z; y * 256 < ne; y += 4) {
        const int m0 = y * 256;

        // A source pointers (gathered for MODE0)
        const bf16_t* asrc[2][2];
#pragma unroll
        for (int h = 0; h < 2; ++h)
#pragma unroll
            for (int q = 0; q < 2; ++q) {
                int mm = m0 + h * 128 + artq0 + q * 8;
                if (MODE == 0) {
                    int tok = tok_ids[b0 + (mm < ne ? mm : ne - 1)];
                    asrc[h][q] = A + (size_t)tok * KD + lcol;
                } else {
                    int rr = (mm < ne ? mm : ne - 1) + b0;
                    asrc[h][q] = A + (size_t)rr * KD + lcol;
                }
            }
        const bf16_t* bptr[2][2] = {{bsrc[0][0], bsrc[0][1]}, {bsrc[1][0], bsrc[1][1]}};

        f32x4 acc[8][4];
#pragma unroll
        for (int i = 0; i < 8; ++i)
#pragma unroll
            for (int j = 0; j < 4; ++j) acc[i][j] = (f32x4){0.f, 0.f, 0.f, 0.f};

        // prologue: stage K-tile 0 into buffer 0
#pragma unroll
        for (int h = 0; h < 2; ++h)
#pragma unroll
            for (int q = 0; q < 2; ++q) {
                GLL(asrc[h][q], lA + dstA[h][q]);
                GLL(bptr[h][q], lB + dstA[h][q]);
            }
        asm volatile("s_waitcnt vmcnt(0)" ::: "memory");
        __builtin_amdgcn_s_barrier();

        for (int kt = 0; kt < KT; ++kt) {
            const int cb = kt & 1, nb = cb ^ 1;
            const bf16_t* rA = lA + cb * ABUF;
            const bf16_t* rB = lB + cb * ABUF;
            bf16x8 fa[8][2], fb[4][2];

            // ---- W0: stage A' | read fa(mh0) + all fb | MFMA q0 ----
            if (kt + 1 < KT) {
#pragma unroll
                for (int h = 0; h < 2; ++h)
#pragma unroll
                    for (int q = 0; q < 2; ++q)
                        GLL(asrc[h][q] + (kt + 1) * 64, lA + nb * ABUF + dstA[h][q]);
            }
#pragma unroll
            for (int i = 0; i < 4; ++i)
#pragma unroll
                for (int kk = 0; kk < 2; ++kk)
                    fa[i][kk] = *(const bf16x8*)(rA + (wm * 128 + i * 16 + lr) * 64 + (pc0 ^ (kk * 32)));
#pragma unroll
            for (int j = 0; j < 4; ++j)
#pragma unroll
                for (int kk = 0; kk < 2; ++kk)
                    fb[j][kk] = *(const bf16x8*)(rB + (wn * 64 + j * 16 + lr) * 64 + (pc0 ^ (kk * 32)));
            __builtin_amdgcn_sched_barrier(0);
            __builtin_amdgcn_s_setprio(1);
#pragma unroll
            for (int i = 0; i < 4; ++i)
#pragma unroll
                for (int j = 0; j < 2; ++j)
#pragma unroll
                    for (int kk = 0; kk < 2; ++kk)
                        acc[i][j] = __builtin_amdgcn_mfma_f32_16x16x32_bf16(fb[j][kk], fa[i][kk], acc[i][j], 0, 0, 0);
            __builtin_amdgcn_s_setprio(0);
            __builtin_amdgcn_s_barrier();

            // ---- W1: stage B' | read fa(mh1) | MFMA q1 ----
            if (kt + 1 < KT) {
#pragma unroll
                for (int h = 0; h < 2; ++h)
#pragma unroll
                    for (int q = 0; q < 2; ++q)
                        GLL(bptr[h][q] + (kt + 1) * 64, lB + nb * ABUF + dstA[h][q]);
            }
#pragma unroll
            for (int i = 0; i < 4; ++i)
#pragma unroll
                for (int kk = 0; kk < 2; ++kk)
                    fa[4 + i][kk] = *(const bf16x8*)(rA + (wm * 128 + 64 + i * 16 + lr) * 64 + (pc0 ^ (kk * 32)));
            __builtin_amdgcn_sched_barrier(0);
            __builtin_amdgcn_s_setprio(1);
#pragma unroll
            for (int i = 0; i < 4; ++i)
#pragma unroll
                for (int j = 2; j < 4; ++j)
#pragma unroll
                    for (int kk = 0; kk < 2; ++kk)
                        acc[i][j] = __builtin_amdgcn_mfma_f32_16x16x32_bf16(fb[j][kk], fa[i][kk], acc[i][j], 0, 0, 0);
            __builtin_amdgcn_s_setprio(0);
            __builtin_amdgcn_s_barrier();

            // ---- W2: MFMA q2+q3 | vmcnt(0) | barrier ----
            __builtin_amdgcn_sched_barrier(0);
            __builtin_amdgcn_s_setprio(1);
#pragma unroll
            for (int i = 0; i < 4; ++i)
#pragma unroll
                for (int j = 0; j < 4; ++j)
#pragma unroll
                    for (int kk = 0; kk < 2; ++kk)
                        acc[4 + i][j] = __builtin_amdgcn_mfma_f32_16x16x32_bf16(fb[j][kk], fa[4 + i][kk], acc[4 + i][j], 0, 0, 0);
            __builtin_amdgcn_s_setprio(0);
            if (kt + 1 < KT) asm volatile("s_waitcnt vmcnt(0)" ::: "memory");
            __builtin_amdgcn_s_barrier();
        }

        // ---------------- epilogue ----------------
#pragma unroll
        for (int i = 0; i < 8; ++i) {
            int ml = wm * 128 + (i >> 2) * 64 + (i & 3) * 16 + lr;
            int gm = m0 + ml;
            bool valid = gm < ne;
            int tok = 0; float gv = 0.f;
            if (MODE == 1 && valid) { tok = tok_ids[b0 + gm]; gv = sgate[b0 + gm]; }
#pragma unroll
            for (int j = 0; j < 4; ++j) {
                int gn = n0 + wn * 64 + j * 16 + lq * 4;
                if (valid) {
                    f32x4 bv = *(const f32x4*)&bias[(size_t)e * ND + gn];
                    if (MODE == 0) {
                        bf16x4 hv;
#pragma unroll
                        for (int r2 = 0; r2 < 4; ++r2)
                            hv[r2] = (__bf16)fmaxf(acc[i][j][r2] + bv[r2], 0.f);
                        *(bf16x4*)&hbuf[(size_t)(b0 + gm) * HID + gn] = hv;
                    } else {
#pragma unroll
                        for (int r2 = 0; r2 < 4; ++r2)
                            atomicAdd(&out[(size_t)tok * OUTD + gn + r2],
                                      gv * (acc[i][j][r2] + bv[r2]));
                    }
                }
            }
        }
    }
#undef GLL
}

extern "C" void kernel_launch(void* const* d_in, const int* in_sizes, int n_in,
                              void* d_out, int out_size, void* d_ws, size_t ws_size,
                              hipStream_t stream) {
    const float* x  = (const float*)d_in[0];
    const float* wg = (const float*)d_in[1];
    const float* w1 = (const float*)d_in[2];
    const float* b1 = (const float*)d_in[3];
    const float* w2 = (const float*)d_in[4];
    const float* b2 = (const float*)d_in[5];
    float* out = (float*)d_out;

    char* ws = (char*)d_ws;
    size_t o = 0;
    auto alloc = [&](size_t b) { size_t r = o; o = (o + b + 255) & ~(size_t)255; return r; };
    int*    counts  = (int*)(ws + alloc(NE * 4));
    int*    cursor  = (int*)(ws + alloc(NE * 4));
    int*    bases   = (int*)(ws + alloc(NE * 4));
    float*  imp     = (float*)(ws + alloc(NE * 4));
    int*    tki     = (int*)(ws + alloc(SLOTS * 4));
    float*  tkg     = (float*)(ws + alloc(SLOTS * 4));
    int*    tok_ids = (int*)(ws + alloc(SLOTS * 4));
    float*  sgate   = (float*)(ws + alloc(SLOTS * 4));
    bf16_t* xb      = (bf16_t*)(ws + alloc((size_t)N_TOK * DIM * 2));
    bf16_t* w1t     = (bf16_t*)(ws + alloc((size_t)NE * HID * DIM * 2));
    bf16_t* w2t     = (bf16_t*)(ws + alloc((size_t)NE * OUTD * HID * 2));
    bf16_t* hbuf    = (bf16_t*)(ws + alloc((size_t)SLOTS_PAD * HID * 2));
    (void)ws_size; (void)n_in; (void)in_sizes;

    static int attr_done = 0;
    hipFuncSetAttribute((const void*)&k_gemm<0>, hipFuncAttributeMaxDynamicSharedMemorySize, 131072);
    hipFuncSetAttribute((const void*)&k_gemm<1>, hipFuncAttributeMaxDynamicSharedMemorySize, 131072);
    (void)attr_done;

    hipMemsetAsync(d_out, 0, (size_t)out_size * 4, stream);   // out must be zero (atomic accum)
    hipMemsetAsync(ws, 0, 1024, stream);                       // counts + cursor

    k_gatecast<<<N_TOK, 64, 0, stream>>>(x, wg, xb, tki, tkg, counts);
    k_transpose<<<dim3(HID / 64, DIM / 64, NE), 256, 0, stream>>>(w1, w1t, DIM, HID);
    k_transpose<<<dim3(OUTD / 64, HID / 64, NE), 256, 0, stream>>>(w2, w2t, HID, OUTD);
    k_importance<<<NE, 256, 0, stream>>>(tki, tkg, imp);
    k_finalize<<<1, 64, 0, stream>>>(imp, counts, bases, out + (size_t)N_TOK * OUTD);
    k_build<<<SLOTS / 256, 256, 0, stream>>>(tki, tkg, bases, cursor, tok_ids, sgate);

    k_gemm<0><<<NE * (HID / 256) * 4, 512, 131072, stream>>>(
        xb, w1t, b1, tok_ids, sgate, bases, counts, hbuf, nullptr);
    k_gemm<1><<<NE * (OUTD / 256) * 4, 512, 131072, stream>>>(
        hbuf, w2t, b2, tok_ids, sgate, bases, counts, nullptr, out);
}

// Round 5
// 466.767 us; speedup vs baseline: 1.4047x; 1.4047x over previous
//
#include <hip/hip_runtime.h>
#include <hip/hip_bf16.h>
#include <stdint.h>

#define N_TOK 4096
#define DIM   1024
#define NE    8
#define HID   4096
#define OUTD  1024
#define TOPK  2
#define SLOTS (N_TOK*TOPK)
#define SLOTS_PAD (SLOTS+256)

typedef __bf16 bf16_t;
typedef __attribute__((ext_vector_type(8))) __bf16 bf16x8;
typedef __attribute__((ext_vector_type(4))) __bf16 bf16x4;
typedef __attribute__((ext_vector_type(4))) float  f32x4;

// ---------------- fused gating (fp64 logits, top-2, softmax) + x -> bf16 cast ----------------
__global__ void k_gatecast(const float* __restrict__ x, const float* __restrict__ wg,
                           bf16_t* __restrict__ xb,
                           int* __restrict__ tki, float* __restrict__ tkg,
                           int* __restrict__ counts) {
    int n = blockIdx.x;
    int lane = threadIdx.x;            // 64 threads = 1 wave
    const float* xr = x + (size_t)n * DIM;
    double acc[NE];
#pragma unroll
    for (int e = 0; e < NE; ++e) acc[e] = 0.0;
#pragma unroll
    for (int i = 0; i < 4; ++i) {
        int d0 = i * 256 + lane * 4;
        float4 v = *(const float4*)&xr[d0];
        bf16x4 o;
        o[0] = (__bf16)v.x; o[1] = (__bf16)v.y; o[2] = (__bf16)v.z; o[3] = (__bf16)v.w;
        *(bf16x4*)&xb[(size_t)n * DIM + d0] = o;
        const float* wr = wg + (size_t)d0 * NE;
#pragma unroll
        for (int j = 0; j < 4; ++j) {
            double xv = (double)((&v.x)[j]);
#pragma unroll
            for (int e = 0; e < NE; ++e) acc[e] += xv * (double)wr[j * NE + e];
        }
    }
#pragma unroll
    for (int e = 0; e < NE; ++e)
        for (int off = 32; off > 0; off >>= 1) acc[e] += __shfl_xor(acc[e], off);
    if (lane == 0) {
        int i0 = 0; double v0 = acc[0];
#pragma unroll
        for (int e = 1; e < NE; ++e) if (acc[e] > v0) { v0 = acc[e]; i0 = e; }
        int i1 = -1; double v1 = -1e300;
#pragma unroll
        for (int e = 0; e < NE; ++e) if (e != i0 && acc[e] > v1) { v1 = acc[e]; i1 = e; }
        double e1 = exp(v1 - v0);
        double s = 1.0 + e1;
        tki[n*2]   = i0;  tki[n*2+1] = i1;
        tkg[n*2]   = (float)(1.0 / s);
        tkg[n*2+1] = (float)(e1 / s);
        atomicAdd(&counts[i0], 1);
        atomicAdd(&counts[i1], 1);
    }
}

// ---------------- importance: deterministic per-expert reduction ----------------
__global__ void k_importance(const int* __restrict__ tki, const float* __restrict__ tkg,
                             float* __restrict__ imp) {
    int e = blockIdx.x, t = threadIdx.x;
    __shared__ float red[256];
    float s = 0.f;
    for (int i = t; i < SLOTS; i += 256) s += (tki[i] == e) ? tkg[i] : 0.f;
    red[t] = s; __syncthreads();
    for (int off = 128; off > 0; off >>= 1) {
        if (t < off) red[t] += red[t + off];
        __syncthreads();
    }
    if (t == 0) imp[e] = red[0];
}

// ---------------- aux loss + prefix-sum bases ----------------
__global__ void k_finalize(const float* __restrict__ imp, const int* __restrict__ counts,
                           int* __restrict__ bases, float* __restrict__ aux_out) {
    if (threadIdx.x == 0 && blockIdx.x == 0) {
        float m = 0.f;
        for (int e = 0; e < NE; ++e) m += imp[e];
        m /= (float)NE;
        float var = 0.f;
        for (int e = 0; e < NE; ++e) { float d = imp[e] - m; var += d * d; }
        var /= (float)NE;
        aux_out[0] = 0.01f * var / (m * m + 1e-10f);
        int b = 0;
        for (int e = 0; e < NE; ++e) { bases[e] = b; b += counts[e]; }
    }
}

// ---------------- build per-expert token lists + inverse slot map ----------------
__global__ void k_build(const int* __restrict__ tki,
                        const int* __restrict__ bases, int* __restrict__ cursor,
                        int* __restrict__ tok_ids, int* __restrict__ slotmap) {
    int i = blockIdx.x * 256 + threadIdx.x;
    if (i < SLOTS) {
        int e = tki[i];
        int p = atomicAdd(&cursor[e], 1);
        int s = bases[e] + p;
        tok_ids[s] = i >> 1;
        slotmap[i] = s;
    }
}

// ---------------- W [E][R][C] fp32 -> Wt [E][C][R] bf16, 64x64 tiles ----------------
__global__ void k_transpose(const float* __restrict__ src, bf16_t* __restrict__ dst,
                            int R, int C) {
    __shared__ float tile[64][65];
    const size_t slab = (size_t)R * C;
    const float* s = src + slab * blockIdx.z;
    bf16_t*      d = dst + slab * blockIdx.z;
    int c0 = blockIdx.x * 64, r0 = blockIdx.y * 64;
    int tx = threadIdx.x & 15;
    int ty = threadIdx.x >> 4;
#pragma unroll
    for (int p = 0; p < 4; ++p) {
        int rr = p * 16 + ty;
        float4 v = *(const float4*)&s[(size_t)(r0 + rr) * C + c0 + tx * 4];
        tile[rr][tx*4+0] = v.x; tile[rr][tx*4+1] = v.y;
        tile[rr][tx*4+2] = v.z; tile[rr][tx*4+3] = v.w;
    }
    __syncthreads();
#pragma unroll
    for (int p = 0; p < 4; ++p) {
        int rr = p * 16 + ty;          // dst row (= source column)
        int cc = tx * 4;               // dst col (= source row)
        bf16x4 o;
        o[0] = (__bf16)tile[cc+0][rr]; o[1] = (__bf16)tile[cc+1][rr];
        o[2] = (__bf16)tile[cc+2][rr]; o[3] = (__bf16)tile[cc+3][rr];
        *(bf16x4*)&d[(size_t)(c0 + rr) * R + r0 + cc] = o;
    }
}

// ---------------- grouped GEMM, 256x256 tile, BK=64, 8 waves (2M x 4N), 2-phase ----------------
// m248-anchored: stage(next K-tile, 8 GLL/wave) -> compute(cur: 16 ds_read, 64 MFMA,
// fragments phase-local) -> ONE __syncthreads() per K-tile (vmcnt0+lgkm0+barrier).
// Both-sides LDS swizzle (rule #21): phys col = logical ^ ((row&7)<<3); GLL dest linear,
// source col pre-permuted ((L&7)^(L>>3))<<3. Expert pinned to XCD (bid&7).
// MODE 0: hbuf[slot] = relu(x_gather @ W1t^T + b1)   (bf16)
// MODE 1: ybuf[slot] = h @ W2t^T + b2                (bf16, unscaled; combine later)
template <int MODE>
__global__ __launch_bounds__(512, 2)
void k_gemm(const bf16_t* __restrict__ A,    // MODE0: xb [N][DIM]; MODE1: hbuf [SLOTS_PAD][HID]
            const bf16_t* __restrict__ Bt,   // MODE0: w1t [E][HID][DIM]; MODE1: w2t [E][OUTD][HID]
            const float* __restrict__ bias,  // MODE0: b1 [E][HID]; MODE1: b2 [E][OUTD]
            const int* __restrict__ tok_ids,
            const int* __restrict__ bases,
            const int* __restrict__ counts,
            bf16_t* __restrict__ Y) {        // MODE0: hbuf; MODE1: ybuf
    constexpr int KD = (MODE == 0) ? DIM : HID;
    constexpr int ND = (MODE == 0) ? HID : OUTD;
    constexpr int NP = ND / 256;            // 16 / 4
    constexpr int KT = KD / 64;             // 16 / 64
    constexpr int ABUF = 256 * 64;          // elems per buffer half
    constexpr int ZB = 8;

    const int e     = blockIdx.x & 7;       // expert pinned to XCD
    const int rest  = blockIdx.x >> 3;
    const int panel = rest % NP;
    const int z     = rest / NP;            // [0, ZB)
    const int ne = counts[e];
    const int b0 = bases[e];
    const int n0 = panel * 256;

    extern __shared__ bf16_t lds[];         // 2*ABUF (A) + 2*ABUF (B) = 128 KB
    bf16_t* lA = lds;
    bf16_t* lB = lds + 2 * ABUF;

    const int t = threadIdx.x, w = t >> 6, L = t & 63;
    const int wm = w >> 2, wn = w & 3;      // 2 x 4 wave grid; per-wave out 128x64
    const int lr = L & 15, lq = L >> 4;

    const int rowl   = L >> 3;                      // 0..7 within an 8-row stage group
    const int srccol = (((L & 7) ^ rowl) << 3);     // pre-swizzled source col (elems)
    const int dst0   = w * 2048;                    // wave stage base (elems): (w*4)*8*64
    const int pcol   = (lq * 8) ^ ((lr & 7) * 8);   // swizzled fragment col base

    // B stage pointers (rows fixed per block)
    const bf16_t* bptr[4];
#pragma unroll
    for (int s = 0; s < 4; ++s)
        bptr[s] = Bt + ((size_t)e * ND + n0 + (w * 4 + s) * 8 + rowl) * KD + srccol;

#define GLL(srcp, dstp) __builtin_amdgcn_global_load_lds( \
        (const __attribute__((address_space(1))) uint32_t*)(srcp), \
        (__attribute__((address_space(3))) uint32_t*)(dstp), 16, 0, 0)

    for (int y = z; y * 256 < ne; y += ZB) {
        const int m0 = y * 256;

        // A stage pointers (token-gathered for MODE0)
        const bf16_t* aptr[4];
#pragma unroll
        for (int s = 0; s < 4; ++s) {
            int mm = m0 + (w * 4 + s) * 8 + rowl;
            int rr = (mm < ne) ? mm : (ne - 1);
            if (MODE == 0) {
                int tok = tok_ids[b0 + rr];
                aptr[s] = A + (size_t)tok * KD + srccol;
            } else {
                aptr[s] = A + (size_t)(b0 + rr) * KD + srccol;
            }
        }

        f32x4 acc[8][4];
#pragma unroll
        for (int i = 0; i < 8; ++i)
#pragma unroll
            for (int j = 0; j < 4; ++j) acc[i][j] = (f32x4){0.f, 0.f, 0.f, 0.f};

        // prologue: stage K-tile 0 into buffer 0
#pragma unroll
        for (int s = 0; s < 4; ++s) {
            GLL(aptr[s], lA + dst0 + s * 512);
            GLL(bptr[s], lB + dst0 + s * 512);
        }
        __syncthreads();

        for (int kt = 0; kt < KT; ++kt) {
            const int cb = kt & 1, nb = cb ^ 1;

            // stage next K-tile into the other buffer (overlaps with compute below)
            if (kt + 1 < KT) {
#pragma unroll
                for (int s = 0; s < 4; ++s) {
                    GLL(aptr[s] + (kt + 1) * 64, lA + nb * ABUF + dst0 + s * 512);
                    GLL(bptr[s] + (kt + 1) * 64, lB + nb * ABUF + dst0 + s * 512);
                }
            }

            // compute current buffer; fragments phase-local to cap VGPR pressure
            const bf16_t* rA = lA + cb * ABUF + (wm * 128) * 64;
            const bf16_t* rB = lB + cb * ABUF + (wn * 64) * 64;
            bf16x8 fb[4][2];
#pragma unroll
            for (int j = 0; j < 4; ++j)
#pragma unroll
                for (int kk = 0; kk < 2; ++kk)
                    fb[j][kk] = *(const bf16x8*)(rB + (j * 16 + lr) * 64 + (pcol ^ (kk << 5)));
#pragma unroll
            for (int mh = 0; mh < 2; ++mh) {
                bf16x8 fa[4][2];
#pragma unroll
                for (int i = 0; i < 4; ++i)
#pragma unroll
                    for (int kk = 0; kk < 2; ++kk)
                        fa[i][kk] = *(const bf16x8*)(rA + (mh * 64 + i * 16 + lr) * 64 + (pcol ^ (kk << 5)));
                __builtin_amdgcn_s_setprio(1);
#pragma unroll
                for (int i = 0; i < 4; ++i)
#pragma unroll
                    for (int j = 0; j < 4; ++j)
#pragma unroll
                        for (int kk = 0; kk < 2; ++kk)
                            acc[mh * 4 + i][j] = __builtin_amdgcn_mfma_f32_16x16x32_bf16(
                                fb[j][kk], fa[i][kk], acc[mh * 4 + i][j], 0, 0, 0);
                __builtin_amdgcn_s_setprio(0);
            }
            __syncthreads();   // vmcnt(0)+lgkmcnt(0)+barrier: nb ready, cb free
        }

        // ---------------- epilogue: bf16 store (no atomics) ----------------
#pragma unroll
        for (int a = 0; a < 8; ++a) {
            int ml = wm * 128 + (a >> 2) * 64 + (a & 3) * 16 + lr;
            int gm = m0 + ml;
            if (gm < ne) {
#pragma unroll
                for (int j = 0; j < 4; ++j) {
                    int gn = n0 + wn * 64 + j * 16 + lq * 4;
                    f32x4 bv = *(const f32x4*)&bias[(size_t)e * ND + gn];
                    bf16x4 hv;
#pragma unroll
                    for (int r2 = 0; r2 < 4; ++r2) {
                        float v = acc[a][j][r2] + bv[r2];
                        if (MODE == 0) v = fmaxf(v, 0.f);
                        hv[r2] = (__bf16)v;
                    }
                    *(bf16x4*)&Y[(size_t)(b0 + gm) * ND + gn] = hv;
                }
            }
        }
    }
#undef GLL
}

// ---------------- combine: out[n] = g0*y[s0] + g1*y[s1] (fp32) ----------------
__global__ void k_combine(const bf16_t* __restrict__ ybuf,
                          const int* __restrict__ slotmap,
                          const float* __restrict__ tkg,
                          float* __restrict__ out) {
    int n = blockIdx.x;
    int d = threadIdx.x * 4;
    int s0 = slotmap[2 * n], s1 = slotmap[2 * n + 1];
    float g0 = tkg[2 * n],  g1 = tkg[2 * n + 1];
    bf16x4 y0 = *(const bf16x4*)&ybuf[(size_t)s0 * OUTD + d];
    bf16x4 y1 = *(const bf16x4*)&ybuf[(size_t)s1 * OUTD + d];
    f32x4 o;
#pragma unroll
    for (int r = 0; r < 4; ++r)
        o[r] = g0 * (float)y0[r] + g1 * (float)y1[r];
    *(f32x4*)&out[(size_t)n * OUTD + d] = o;
}

extern "C" void kernel_launch(void* const* d_in, const int* in_sizes, int n_in,
                              void* d_out, int out_size, void* d_ws, size_t ws_size,
                              hipStream_t stream) {
    const float* x  = (const float*)d_in[0];
    const float* wg = (const float*)d_in[1];
    const float* w1 = (const float*)d_in[2];
    const float* b1 = (const float*)d_in[3];
    const float* w2 = (const float*)d_in[4];
    const float* b2 = (const float*)d_in[5];
    float* out = (float*)d_out;

    char* ws = (char*)d_ws;
    size_t o = 0;
    auto alloc = [&](size_t b) { size_t r = o; o = (o + b + 255) & ~(size_t)255; return r; };
    int*    counts  = (int*)(ws + alloc(NE * 4));
    int*    cursor  = (int*)(ws + alloc(NE * 4));
    int*    bases   = (int*)(ws + alloc(NE * 4));
    float*  imp     = (float*)(ws + alloc(NE * 4));
    int*    tki     = (int*)(ws + alloc(SLOTS * 4));
    float*  tkg     = (float*)(ws + alloc(SLOTS * 4));
    int*    tok_ids = (int*)(ws + alloc(SLOTS * 4));
    int*    slotmap = (int*)(ws + alloc(SLOTS * 4));
    bf16_t* xb      = (bf16_t*)(ws + alloc((size_t)N_TOK * DIM * 2));
    size_t  w1t_off = alloc((size_t)NE * HID * DIM * 2);
    bf16_t* w1t     = (bf16_t*)(ws + w1t_off);
    bf16_t* ybuf    = (bf16_t*)(ws + w1t_off);   // aliases w1t (dead after GEMM-1)
    bf16_t* w2t     = (bf16_t*)(ws + alloc((size_t)NE * OUTD * HID * 2));
    bf16_t* hbuf    = (bf16_t*)(ws + alloc((size_t)SLOTS_PAD * HID * 2));
    (void)ws_size; (void)n_in; (void)in_sizes;

    hipFuncSetAttribute((const void*)&k_gemm<0>, hipFuncAttributeMaxDynamicSharedMemorySize, 131072);
    hipFuncSetAttribute((const void*)&k_gemm<1>, hipFuncAttributeMaxDynamicSharedMemorySize, 131072);

    hipMemsetAsync(ws, 0, 1024, stream);   // counts + cursor

    k_gatecast<<<N_TOK, 64, 0, stream>>>(x, wg, xb, tki, tkg, counts);
    k_transpose<<<dim3(HID / 64, DIM / 64, NE), 256, 0, stream>>>(w1, w1t, DIM, HID);
    k_transpose<<<dim3(OUTD / 64, HID / 64, NE), 256, 0, stream>>>(w2, w2t, HID, OUTD);
    k_importance<<<NE, 256, 0, stream>>>(tki, tkg, imp);
    k_finalize<<<1, 64, 0, stream>>>(imp, counts, bases, out + (size_t)N_TOK * OUTD);
    k_build<<<SLOTS / 256, 256, 0, stream>>>(tki, bases, cursor, tok_ids, slotmap);

    k_gemm<0><<<NE * (HID / 256) * 8, 512, 131072, stream>>>(
        xb, w1t, b1, tok_ids, bases, counts, hbuf);
    k_gemm<1><<<NE * (OUTD / 256) * 8, 512, 131072, stream>>>(
        hbuf, w2t, b2, tok_ids, bases, counts, ybuf);

    k_combine<<<N_TOK, 256, 0, stream>>>(ybuf, slotmap, tkg, out);
}